// Round 3
// baseline (494.041 us; speedup 1.0000x reference)
//
#include <hip/hip_runtime.h>
#include <math.h>

#define NB 8
#define NN 2048
// log2-domain: everything (u, v, LSE) kept in log2 units.
// out = 2^(A*SCALE2 - u2 - v2) == e^(A*20 - u_e - v_e).  SCALE2 = 20*log2(e).
#define SCALE2 28.853900817779268f
#define RPW 8                 // rows per wave
#define BROWS 32              // rows per block (4 waves * RPW)
#define CHB (NN / BROWS)      // 64 partial chunks per matrix

// raw-instruction transcendentals: v_exp_f32 is 2^x, v_log_f32 is log2(x).
#if __has_builtin(__builtin_amdgcn_exp2f)
__device__ __forceinline__ float fexp2(float x) { return __builtin_amdgcn_exp2f(x); }
#else
__device__ __forceinline__ float fexp2(float x) { return exp2f(x); }
#endif
#if __has_builtin(__builtin_amdgcn_logf)
__device__ __forceinline__ float flog2(float x) { return __builtin_amdgcn_logf(x); }
#else
__device__ __forceinline__ float flog2(float x) { return log2f(x); }
#endif

__device__ __forceinline__ float wave_max(float x) {
#pragma unroll
    for (int off = 32; off >= 1; off >>= 1)
        x = fmaxf(x, __shfl_xor(x, off, 64));
    return x;
}
__device__ __forceinline__ float wave_sum(float x) {
#pragma unroll
    for (int off = 32; off >= 1; off >>= 1)
        x += __shfl_xor(x, off, 64);
    return x;
}

// ---------------- fused path ----------------
// One wave owns RPW rows: u[row] = LSE2_c(A*SCALE2 - v).  Column partials
// s[c] += exp2(A*SCALE2 - v[c] - u[row]).  The 4 waves of a block reduce
// their partials in LDS, so ps has one chunk per 32 rows (CHB per matrix).
// Latency fixes vs round-0: next-row register prefetch, pairwise tree
// reductions, exp2/log2 domain, hoisted v.
__global__ __launch_bounds__(256, 2) void fused_iter(const float* __restrict__ A,
                                                     const float* __restrict__ v,
                                                     float* __restrict__ u,
                                                     float* __restrict__ ps) {
    const int wid  = threadIdx.x >> 6;
    const int lane = threadIdx.x & 63;
    const int b    = blockIdx.x >> 6;          // 64 blocks per matrix
    const int blk  = blockIdx.x & 63;
    const int row0 = blk * BROWS + wid * RPW;

    // hoist v for this matrix (row-invariant); negation is a free fma modifier
    float vv[32];
    {
        const float4* v4 = (const float4*)(v + (size_t)b * NN);
#pragma unroll
        for (int k = 0; k < 8; ++k) {
            float4 t = v4[lane + (k << 6)];
            vv[4 * k + 0] = t.x; vv[4 * k + 1] = t.y;
            vv[4 * k + 2] = t.z; vv[4 * k + 3] = t.w;
        }
    }

    float s[32];
#pragma unroll
    for (int i = 0; i < 32; ++i) s[i] = 0.f;

    // prologue: prefetch first row into registers
    float nxt[32];
    {
        const float4* a4 = (const float4*)(A + ((size_t)b * NN + row0) * NN);
#pragma unroll
        for (int k = 0; k < 8; ++k) {
            float4 a = a4[lane + (k << 6)];
            nxt[4 * k + 0] = a.x; nxt[4 * k + 1] = a.y;
            nxt[4 * k + 2] = a.z; nxt[4 * k + 3] = a.w;
        }
    }

#pragma unroll 1
    for (int r = 0; r < RPW; ++r) {
        // consume prefetched row
        float e[32];
#pragma unroll
        for (int i = 0; i < 32; ++i) e[i] = fmaf(nxt[i], SCALE2, -vv[i]);

        // issue next row's loads BEFORE the reduction chains (latency hiding)
        if (r + 1 < RPW) {
            const float4* a4 =
                (const float4*)(A + ((size_t)b * NN + row0 + r + 1) * NN);
#pragma unroll
            for (int k = 0; k < 8; ++k) {
                float4 a = a4[lane + (k << 6)];
                nxt[4 * k + 0] = a.x; nxt[4 * k + 1] = a.y;
                nxt[4 * k + 2] = a.z; nxt[4 * k + 3] = a.w;
            }
        }

        // in-register pairwise tree max (short dep chain)
        float t[16];
#pragma unroll
        for (int i = 0; i < 16; ++i) t[i] = fmaxf(e[i], e[i + 16]);
#pragma unroll
        for (int off = 8; off >= 1; off >>= 1)
#pragma unroll
            for (int i = 0; i < off; ++i) t[i] = fmaxf(t[i], t[i + off]);
        float m = wave_max(t[0]);

#pragma unroll
        for (int i = 0; i < 32; ++i) e[i] = fexp2(e[i] - m);

        // pairwise tree sum
#pragma unroll
        for (int i = 0; i < 16; ++i) t[i] = e[i] + e[i + 16];
#pragma unroll
        for (int off = 8; off >= 1; off >>= 1)
#pragma unroll
            for (int i = 0; i < off; ++i) t[i] += t[i + off];
        float S = wave_sum(t[0]);

        if (lane == 0) u[b * NN + row0 + r] = m + flog2(S);
        float rS = __builtin_amdgcn_rcpf(S);
#pragma unroll
        for (int i = 0; i < 32; ++i) s[i] = fmaf(e[i], rS, s[i]);
    }

    // block-level reduction of the 4 waves' column partials (32 KB LDS)
    __shared__ float4 sm4[4][512];
#pragma unroll
    for (int k = 0; k < 8; ++k)
        sm4[wid][lane + (k << 6)] =
            make_float4(s[4 * k], s[4 * k + 1], s[4 * k + 2], s[4 * k + 3]);
    __syncthreads();

    float4* pbase = (float4*)(ps + ((size_t)b * CHB + blk) * NN);
#pragma unroll
    for (int gg = 0; gg < 2; ++gg) {
        int g = threadIdx.x + (gg << 8);
        float4 x0 = sm4[0][g], x1 = sm4[1][g], x2 = sm4[2][g], x3 = sm4[3][g];
        float4 o;
        o.x = (x0.x + x1.x) + (x2.x + x3.x);
        o.y = (x0.y + x1.y) + (x2.y + x3.y);
        o.z = (x0.z + x1.z) + (x2.z + x3.z);
        o.w = (x0.w + x1.w) + (x2.w + x3.w);
        pbase[g] = o;
    }
}

// v[c] += log2( sum over CHB chunks of ps[b][chunk][c] ).
// Block covers 256 cols (64 float4 groups); 4 waves each sum 16 chunks.
__global__ __launch_bounds__(256) void combine(const float* __restrict__ ps,
                                               float* __restrict__ v) {
    const int l  = threadIdx.x & 63;
    const int g  = threadIdx.x >> 6;           // chunk quarter 0..3
    const int b  = blockIdx.x >> 3;
    const int cb = blockIdx.x & 7;             // 256-col tile
    const float4* pb = (const float4*)(ps + (size_t)b * CHB * NN)
                     + (size_t)(g * 16) * (NN / 4) + (cb << 6) + l;
    float4 a0 = make_float4(0.f, 0.f, 0.f, 0.f);
    float4 a1 = make_float4(0.f, 0.f, 0.f, 0.f);
#pragma unroll
    for (int i = 0; i < 16; i += 2) {
        float4 x = pb[(size_t)i * (NN / 4)];
        float4 y = pb[(size_t)(i + 1) * (NN / 4)];
        a0.x += x.x; a0.y += x.y; a0.z += x.z; a0.w += x.w;
        a1.x += y.x; a1.y += y.y; a1.z += y.z; a1.w += y.w;
    }
    __shared__ float4 red[4][64];
    float4 c;
    c.x = a0.x + a1.x; c.y = a0.y + a1.y;
    c.z = a0.z + a1.z; c.w = a0.w + a1.w;
    red[g][l] = c;
    __syncthreads();
    if (threadIdx.x < 64) {
        float4 r0 = red[0][l], r1 = red[1][l], r2 = red[2][l], r3 = red[3][l];
        float4 t;
        t.x = (r0.x + r1.x) + (r2.x + r3.x);
        t.y = (r0.y + r1.y) + (r2.y + r3.y);
        t.z = (r0.z + r1.z) + (r2.z + r3.z);
        t.w = (r0.w + r1.w) + (r2.w + r3.w);
        float4* vp = (float4*)(v + (size_t)b * NN) + (cb << 6) + l;
        float4 cur = *vp;
        cur.x += flog2(t.x);
        cur.y += flog2(t.y);
        cur.z += flog2(t.z);
        cur.w += flog2(t.w);
        *vp = cur;
    }
}

// ---------------- fallback path (small workspace) ----------------
__global__ __launch_bounds__(256) void row_lse(const float* __restrict__ A,
                                               const float* __restrict__ v,
                                               float* __restrict__ u) {
    const int wid  = threadIdx.x >> 6;
    const int lane = threadIdx.x & 63;
    const int row  = blockIdx.x * 4 + wid;
    const int b    = row >> 11;
    const float4* a4 = (const float4*)(A + (size_t)row * NN);
    const float4* v4 = (const float4*)(v + (size_t)b * NN);
    float x[32];
#pragma unroll
    for (int k = 0; k < 8; ++k) {
        float4 a  = a4[lane + (k << 6)];
        float4 vv = v4[lane + (k << 6)];
        x[4 * k + 0] = fmaf(a.x, SCALE2, -vv.x);
        x[4 * k + 1] = fmaf(a.y, SCALE2, -vv.y);
        x[4 * k + 2] = fmaf(a.z, SCALE2, -vv.z);
        x[4 * k + 3] = fmaf(a.w, SCALE2, -vv.w);
    }
    float m = -INFINITY;
#pragma unroll
    for (int i = 0; i < 32; ++i) m = fmaxf(m, x[i]);
    m = wave_max(m);
    float s = 0.f;
#pragma unroll
    for (int i = 0; i < 32; ++i) s += fexp2(x[i] - m);
    s = wave_sum(s);
    if (lane == 0) u[row] = m + flog2(s);
}

__global__ __launch_bounds__(256) void col_lse(const float* __restrict__ A,
                                               const float* __restrict__ u,
                                               float* __restrict__ v) {
    const int b    = blockIdx.x >> 6;
    const int tile = blockIdx.x & 63;
    const int ci   = threadIdx.x & 31;
    const int rg   = threadIdx.x >> 5;
    const int col  = (tile << 5) + ci;
    const float* Ab = A + (size_t)b * NN * NN;
    const float* ub = u + b * NN;
    float m0 = -INFINITY, s0 = 0.f, m1 = -INFINITY, s1 = 0.f;
    for (int r = rg; r < NN; r += 16) {
        float x0 = fmaf(Ab[(size_t)r * NN + col], SCALE2, -ub[r]);
        float x1 = fmaf(Ab[(size_t)(r + 8) * NN + col], SCALE2, -ub[r + 8]);
        float nm0 = fmaxf(m0, x0);
        s0 = s0 * fexp2(m0 - nm0) + fexp2(x0 - nm0); m0 = nm0;
        float nm1 = fmaxf(m1, x1);
        s1 = s1 * fexp2(m1 - nm1) + fexp2(x1 - nm1); m1 = nm1;
    }
    float m = fmaxf(m0, m1);
    float s = s0 * fexp2(m0 - m) + s1 * fexp2(m1 - m);
    __shared__ float sm[8][33];
    __shared__ float ss[8][33];
    sm[rg][ci] = m; ss[rg][ci] = s;
    __syncthreads();
    if (threadIdx.x < 32) {
        const int c = threadIdx.x;
        float M = sm[0][c], S = ss[0][c];
#pragma unroll
        for (int g = 1; g < 8; ++g) {
            float mg = sm[g][c], sg = ss[g][c];
            float nM = fmaxf(M, mg);
            S = S * fexp2(M - nM) + sg * fexp2(mg - nM);
            M = nM;
        }
        v[b * NN + (tile << 5) + c] = M + flog2(S);
    }
}

// ---------------- final ----------------
__global__ __launch_bounds__(256) void final_exp(const float* __restrict__ A,
                                                 const float* __restrict__ u,
                                                 const float* __restrict__ v,
                                                 float* __restrict__ out) {
    const int i4    = blockIdx.x * 256 + threadIdx.x;
    const int rglob = i4 >> 9;
    const int c4    = i4 & 511;
    const int b     = rglob >> 11;
    const float uu  = u[rglob];
    float4 a  = ((const float4*)A)[i4];
    float4 vv = ((const float4*)(v + (size_t)b * NN))[c4];
    float4 o;
    o.x = fexp2(fmaf(a.x, SCALE2, -uu) - vv.x);
    o.y = fexp2(fmaf(a.y, SCALE2, -uu) - vv.y);
    o.z = fexp2(fmaf(a.z, SCALE2, -uu) - vv.z);
    o.w = fexp2(fmaf(a.w, SCALE2, -uu) - vv.w);
    ((float4*)out)[i4] = o;
}

extern "C" void kernel_launch(void* const* d_in, const int* in_sizes, int n_in,
                              void* d_out, int out_size, void* d_ws, size_t ws_size,
                              hipStream_t stream) {
    const float* A = (const float*)d_in[0];
    float* out = (float*)d_out;
    float* u  = (float*)d_ws;                 // NB*NN floats (log2 units)
    float* v  = u + NB * NN;                  // NB*NN floats (log2 units)
    float* ps = v + NB * NN;                  // NB*CHB*NN floats (fused path)

    const size_t need =
        ((size_t)2 * NB * NN + (size_t)NB * CHB * NN) * sizeof(float);

    hipMemsetAsync(v, 0, NB * NN * sizeof(float), stream);

    if (ws_size >= need) {
        for (int it = 0; it < 10; ++it) {
            fused_iter<<<NB * CHB, 256, 0, stream>>>(A, v, u, ps);
            combine<<<NB * 8, 256, 0, stream>>>(ps, v);
        }
    } else {
        for (int it = 0; it < 10; ++it) {
            row_lse<<<NB * NN / 4, 256, 0, stream>>>(A, v, u);
            col_lse<<<NB * (NN / 32), 256, 0, stream>>>(A, u, v);
        }
    }
    final_exp<<<NB * NN * NN / 1024, 256, 0, stream>>>(A, u, v, out);
}